// Round 4
// baseline (169.880 us; speedup 1.0000x reference)
//
#include <hip/hip_runtime.h>
#include <hip/hip_bf16.h>
#include <cstdio>

typedef __hip_bfloat16 bf16;
typedef __bf16 bf16x8 __attribute__((ext_vector_type(8)));
typedef float f32x4 __attribute__((ext_vector_type(4)));

#define B_DIM 4
#define T_DIM 4096
#define D_DIM 1024
#define NC 64   // chunks along T
#define LC 64   // chunk length; NC*LC == T_DIM

// ---------------------------------------------------------------- weight cast
__global__ __launch_bounds__(256) void cast_w_kernel(
    const float* __restrict__ gw, const float* __restrict__ ow,
    bf16* __restrict__ gw16, bf16* __restrict__ ow16, int n) {
  int i = blockIdx.x * 256 + threadIdx.x;
  if (i < n) {
    gw16[i] = __float2bfloat16(gw[i]);
    ow16[i] = __float2bfloat16(ow[i]);
  }
}

// ---------------------------------------------------------------- SSM pass 1
// Per-chunk local scan with h_in = 0; emit terminal state hfin[b][c][d].
__global__ __launch_bounds__(256) void ssm_pass1(
    const float* __restrict__ x, const float* __restrict__ A,
    const float* __restrict__ Bp, float* __restrict__ hfin) {
  const int tid  = threadIdx.x;
  const int dblk = blockIdx.x & 3;           // D/256 = 4
  const int c    = (blockIdx.x >> 2) & (NC - 1);
  const int b    = blockIdx.x >> 8;          // / (4*NC)
  const int d    = dblk * 256 + tid;
  const float a = A[d], bp = Bp[d];
  const float* p = x + ((size_t)(b * T_DIM + c * LC) * D_DIM + d);
  float h = 0.f;
#pragma unroll 4
  for (int i = 0; i < LC; ++i)
    h = fmaf(a, h, bp * p[(size_t)i * D_DIM]);
  hfin[(b * NC + c) * D_DIM + d] = h;
}

// ---------------------------------------------------------------- SSM pass 2
// Serial combine over the NC chunk summaries: h_in[c] = A^LC * h_in[c-1] + hfin[c-1].
__global__ __launch_bounds__(256) void ssm_pass2(
    const float* __restrict__ A, const float* __restrict__ hfin,
    float* __restrict__ hin) {
  const int idx = blockIdx.x * 256 + threadIdx.x;  // B*D = 4096
  const int d = idx & (D_DIM - 1);
  const int b = idx >> 10;
  float aL = A[d];
#pragma unroll
  for (int s = 0; s < 6; ++s) aL *= aL;  // A^64 (LC = 2^6)
  float h = 0.f;
  for (int c = 0; c < NC; ++c) {
    const int o = (b * NC + c) * D_DIM + d;
    hin[o] = h;
    h = fmaf(aL, h, hfin[o]);
  }
}

// ---------------------------------------------------------------- SSM pass 3
// Replay local scan seeded with h_in; emit ssm_bf16 = Cp*h and fused x->bf16 cast.
__global__ __launch_bounds__(256) void ssm_pass3(
    const float* __restrict__ x, const float* __restrict__ A,
    const float* __restrict__ Bp, const float* __restrict__ Cp,
    const float* __restrict__ hin, bf16* __restrict__ ssm16,
    bf16* __restrict__ x16) {
  const int tid  = threadIdx.x;
  const int dblk = blockIdx.x & 3;
  const int c    = (blockIdx.x >> 2) & (NC - 1);
  const int b    = blockIdx.x >> 8;
  const int d    = dblk * 256 + tid;
  const float a = A[d], bp = Bp[d], cp = Cp[d];
  float h = hin[(b * NC + c) * D_DIM + d];
  const size_t base = (size_t)(b * T_DIM + c * LC) * D_DIM + d;
#pragma unroll 4
  for (int i = 0; i < LC; ++i) {
    const size_t o = base + (size_t)i * D_DIM;
    const float xv = x[o];
    h = fmaf(a, h, bp * xv);
    ssm16[o] = __float2bfloat16(cp * h);
    x16[o]  = __float2bfloat16(xv);
  }
}

// ---------------------------------------------------------------- GEMM (B^T)
// C[m][e] = sum_k X[m][k] * W[e][k]  (+bias, +epilogue)
// 128x128 tile, 4 waves (2x2), 4x4 16x16x32 fragments per wave, BK=32,
// global_load_lds width 16 staging (m97 structure).
template <bool GATE>
__global__ __launch_bounds__(256) void gemm_bt(
    const bf16* __restrict__ Xm, const bf16* __restrict__ Wm,
    const float* __restrict__ bias, const bf16* __restrict__ ssm,
    bf16* __restrict__ Ybf, float* __restrict__ Yf,
    int M, int N, int K) {
  __shared__ __align__(16) short As[128 * 32];
  __shared__ __align__(16) short Bs[128 * 32];

  const int tid  = threadIdx.x;
  const int lane = tid & 63;
  const int wave = tid >> 6;
  const int wm = wave >> 1, wn = wave & 1;
  const int m0 = blockIdx.x * 128;
  const int n0 = blockIdx.y * 128;

  const int l15 = lane & 15;
  const int lk  = (lane >> 4) << 3;  // k-offset within fragment: 0,8,16,24

  f32x4 acc[4][4] = {};

  for (int k0 = 0; k0 < K; k0 += 32) {
    // ---- stage A(128x32) and B(128x32) bf16 tiles: 512 x 16B chunks each
#pragma unroll
    for (int it = 0; it < 2; ++it) {
      const int chunk = it * 256 + tid;
      const int r  = chunk >> 2;
      const int c8 = (chunk & 3) << 3;
      const bf16* ga = Xm + (size_t)(m0 + r) * K + k0 + c8;
      const bf16* gb = Wm + (size_t)(n0 + r) * K + k0 + c8;
      const int base_chunk = it * 256 + wave * 64;  // wave-uniform LDS base
      __builtin_amdgcn_global_load_lds(
          (const __attribute__((address_space(1))) void*)ga,
          (__attribute__((address_space(3))) void*)(As + base_chunk * 8), 16, 0, 0);
      __builtin_amdgcn_global_load_lds(
          (const __attribute__((address_space(1))) void*)gb,
          (__attribute__((address_space(3))) void*)(Bs + base_chunk * 8), 16, 0, 0);
    }
    __syncthreads();

    bf16x8 af[4], bfr[4];
#pragma unroll
    for (int i = 0; i < 4; ++i) {
      const int row = wm * 64 + i * 16 + l15;
      af[i] = *(const bf16x8*)(As + row * 32 + lk);
      const int col = wn * 64 + i * 16 + l15;
      bfr[i] = *(const bf16x8*)(Bs + col * 32 + lk);
    }
#pragma unroll
    for (int i = 0; i < 4; ++i)
#pragma unroll
      for (int j = 0; j < 4; ++j)
        acc[i][j] = __builtin_amdgcn_mfma_f32_16x16x32_bf16(af[i], bfr[j], acc[i][j], 0, 0, 0);
    __syncthreads();
  }

  // ---- epilogue: C/D layout col = lane&15, row = (lane>>4)*4 + v  [m89/m91]
#pragma unroll
  for (int i = 0; i < 4; ++i) {
#pragma unroll
    for (int j = 0; j < 4; ++j) {
      const int col = n0 + wn * 64 + j * 16 + l15;
      const float bv = bias[col];
#pragma unroll
      for (int v = 0; v < 4; ++v) {
        const int row = m0 + wm * 64 + i * 16 + (lane >> 4) * 4 + v;
        const size_t o = (size_t)row * N + col;
        const float val = acc[i][j][v] + bv;
        if (GATE) {
          const float g = 1.f / (1.f + expf(-val));
          Ybf[o] = __float2bfloat16(g * __bfloat162float(ssm[o]));
        } else {
          Yf[o] = val;
        }
      }
    }
  }
}

// ---------------------------------------------------------------- launch
extern "C" void kernel_launch(void* const* d_in, const int* in_sizes, int n_in,
                              void* d_out, int out_size, void* d_ws, size_t ws_size,
                              hipStream_t stream) {
  const float* x  = (const float*)d_in[0];
  const float* A  = (const float*)d_in[1];
  const float* Bp = (const float*)d_in[2];
  const float* Cp = (const float*)d_in[3];
  const float* gw = (const float*)d_in[4];
  const float* gb = (const float*)d_in[5];
  const float* ow = (const float*)d_in[6];
  const float* ob = (const float*)d_in[7];
  float* out = (float*)d_out;

  // workspace layout (bytes)
  const size_t NEED = 73400320;
  if (ws_size < NEED) {
    fprintf(stderr, "kernel_launch: ws_size %zu < needed %zu\n", ws_size, NEED);
    return;
  }
  char* ws = (char*)d_ws;
  bf16*  x16   = (bf16*)(ws);                   // 33,554,432 B : x cast to bf16
  bf16*  ssm16 = (bf16*)(ws + 33554432);        // 33,554,432 B : ssm, then y in-place
  bf16*  gw16  = (bf16*)(ws + 67108864);        //  2,097,152 B
  bf16*  ow16  = (bf16*)(ws + 69206016);        //  2,097,152 B
  float* hfin  = (float*)(ws + 71303168);       //  1,048,576 B
  float* hin   = (float*)(ws + 72351744);       //  1,048,576 B

  const int M = B_DIM * T_DIM;  // 16384
  const int N = D_DIM, K = D_DIM;

  cast_w_kernel<<<(D_DIM * D_DIM) / 256, 256, 0, stream>>>(gw, ow, gw16, ow16, D_DIM * D_DIM);
  ssm_pass1<<<B_DIM * NC * (D_DIM / 256), 256, 0, stream>>>(x, A, Bp, hfin);
  ssm_pass2<<<(B_DIM * D_DIM) / 256, 256, 0, stream>>>(A, hfin, hin);
  ssm_pass3<<<B_DIM * NC * (D_DIM / 256), 256, 0, stream>>>(x, A, Bp, Cp, hin, ssm16, x16);

  dim3 grid(M / 128, N / 128);
  // gate GEMM: y = sigmoid(x@gw^T + gb) * ssm   (written in-place over ssm16)
  gemm_bt<true><<<grid, 256, 0, stream>>>(x16, gw16, gb, ssm16, ssm16, nullptr, M, N, K);
  // out GEMM: out = y@ow^T + ob  (fp32)
  gemm_bt<false><<<grid, 256, 0, stream>>>(ssm16, ow16, ob, nullptr, nullptr, out, M, N, K);
}

// Round 5
// 155.695 us; speedup vs baseline: 1.0911x; 1.0911x over previous
//
#include <hip/hip_runtime.h>
#include <hip/hip_bf16.h>
#include <cstdio>

typedef __hip_bfloat16 bf16;
typedef __bf16 bf16x8 __attribute__((ext_vector_type(8)));
typedef float f32x4 __attribute__((ext_vector_type(4)));

#define B_DIM 4
#define T_DIM 4096
#define D_DIM 1024
#define NC 64   // chunks along T
#define LC 64   // chunk length; NC*LC == T_DIM

#define M_DIM (B_DIM * T_DIM)  // 16384
#define BM 256
#define BN 256
#define BK 64
#define NT (D_DIM / BK)        // 16 K-tiles
#define GM (M_DIM / BM)        // 64
#define GN (D_DIM / BN)        // 4

// ---------------------------------------------------------------- weight cast
__global__ __launch_bounds__(256) void cast_w_kernel(
    const float* __restrict__ gw, const float* __restrict__ ow,
    bf16* __restrict__ gw16, bf16* __restrict__ ow16, int n) {
  int i = blockIdx.x * 256 + threadIdx.x;
  if (i < n) {
    gw16[i] = __float2bfloat16(gw[i]);
    ow16[i] = __float2bfloat16(ow[i]);
  }
}

// ---------------------------------------------------------------- SSM pass 1
__global__ __launch_bounds__(256) void ssm_pass1(
    const float* __restrict__ x, const float* __restrict__ A,
    const float* __restrict__ Bp, float* __restrict__ hfin) {
  const int tid  = threadIdx.x;
  const int dblk = blockIdx.x & 3;           // D/256 = 4
  const int c    = (blockIdx.x >> 2) & (NC - 1);
  const int b    = blockIdx.x >> 8;          // / (4*NC)
  const int d    = dblk * 256 + tid;
  const float a = A[d], bp = Bp[d];
  const float* p = x + ((size_t)(b * T_DIM + c * LC) * D_DIM + d);
  float h = 0.f;
#pragma unroll 4
  for (int i = 0; i < LC; ++i)
    h = fmaf(a, h, bp * p[(size_t)i * D_DIM]);
  hfin[(b * NC + c) * D_DIM + d] = h;
}

// ---------------------------------------------------------------- SSM pass 2
__global__ __launch_bounds__(256) void ssm_pass2(
    const float* __restrict__ A, const float* __restrict__ hfin,
    float* __restrict__ hin) {
  const int idx = blockIdx.x * 256 + threadIdx.x;  // B*D = 4096
  const int d = idx & (D_DIM - 1);
  const int b = idx >> 10;
  float aL = A[d];
#pragma unroll
  for (int s = 0; s < 6; ++s) aL *= aL;  // A^64 (LC = 2^6)
  float h = 0.f;
  for (int c = 0; c < NC; ++c) {
    const int o = (b * NC + c) * D_DIM + d;
    hin[o] = h;
    h = fmaf(aL, h, hfin[o]);
  }
}

// ---------------------------------------------------------------- SSM pass 3
__global__ __launch_bounds__(256) void ssm_pass3(
    const float* __restrict__ x, const float* __restrict__ A,
    const float* __restrict__ Bp, const float* __restrict__ Cp,
    const float* __restrict__ hin, bf16* __restrict__ ssm16,
    bf16* __restrict__ x16) {
  const int tid  = threadIdx.x;
  const int dblk = blockIdx.x & 3;
  const int c    = (blockIdx.x >> 2) & (NC - 1);
  const int b    = blockIdx.x >> 8;
  const int d    = dblk * 256 + tid;
  const float a = A[d], bp = Bp[d], cp = Cp[d];
  float h = hin[(b * NC + c) * D_DIM + d];
  const size_t base = (size_t)(b * T_DIM + c * LC) * D_DIM + d;
#pragma unroll 4
  for (int i = 0; i < LC; ++i) {
    const size_t o = base + (size_t)i * D_DIM;
    const float xv = x[o];
    h = fmaf(a, h, bp * xv);
    ssm16[o] = __float2bfloat16(cp * h);
    x16[o]  = __float2bfloat16(xv);
  }
}

// ---------------------------------------------------------------- GEMM 256x256
// C[m][e] = sum_k X[m][k] * W[e][k]  (+bias, +epilogue)
// 256x256 tile, BK=64, 8 waves (2M x 4N), per-wave C = 128x64 (8x4 frags),
// double-buffered LDS (128 KiB), global_load_lds width-16 staging,
// one vmcnt(0)+barrier per K-tile (minimum 2-phase recipe, T3 catalog).
template <bool GATE>
__global__ __launch_bounds__(512, 2) void gemm256(
    const bf16* __restrict__ Xm, const bf16* __restrict__ Wm,
    const float* __restrict__ bias, const bf16* __restrict__ ssm,
    bf16* __restrict__ Ybf, float* __restrict__ Yf) {
  __shared__ __align__(16) short As[2][BM * BK];  // 2 x 32 KiB
  __shared__ __align__(16) short Bs[2][BN * BK];  // 2 x 32 KiB

  const int tid  = threadIdx.x;
  const int lane = tid & 63;
  const int wave = tid >> 6;
  const int wm = wave >> 2;           // 0..1
  const int wn = wave & 3;            // 0..3
  const int l15 = lane & 15;
  const int lk8 = (lane >> 4) << 3;   // k-offset in shorts: 0,8,16,24

  // XCD-chunked swizzle: 256 blocks, 8 XCDs, 32 blocks/XCD -> the 4 N-blocks
  // of each M-row land on the same XCD (A-panel L2 reuse).
  const int bid = blockIdx.x;
  const int swz = (bid & 7) * (GM * GN / 8) + (bid >> 3);
  const int m0 = (swz >> 2) * BM;     // swz / GN
  const int n0 = (swz & 3) * BN;      // swz % GN

  // staging map: chunk c = it*512 + tid; row = c>>3, col8 = (c&7)*8 shorts.
  // LDS dest is wave-uniform base (it*512 + wave*64)*16B; HW adds lane*16B.
  int offA[4], offB[4];
#pragma unroll
  for (int it = 0; it < 4; ++it) {
    const int c   = it * 512 + tid;
    const int row = c >> 3;
    const int col = (c & 7) << 3;
    offA[it] = (m0 + row) * D_DIM + col;
    offB[it] = (n0 + row) * D_DIM + col;
  }

  auto STAGE = [&](int buf, int kt) {
#pragma unroll
    for (int it = 0; it < 4; ++it) {
      const bf16* ga = Xm + (size_t)offA[it] + kt * BK;
      const bf16* gb = Wm + (size_t)offB[it] + kt * BK;
      short* la = &As[buf][(it * 512 + wave * 64) * 8];
      short* lb = &Bs[buf][(it * 512 + wave * 64) * 8];
      __builtin_amdgcn_global_load_lds(
          (const __attribute__((address_space(1))) void*)ga,
          (__attribute__((address_space(3))) void*)la, 16, 0, 0);
      __builtin_amdgcn_global_load_lds(
          (const __attribute__((address_space(1))) void*)gb,
          (__attribute__((address_space(3))) void*)lb, 16, 0, 0);
    }
  };

  f32x4 acc[8][4] = {};

  STAGE(0, 0);
  __syncthreads();  // drains vmcnt(0) before barrier (compiler-inserted)

  for (int t = 0; t < NT; ++t) {
    const int cur = t & 1;
    if (t + 1 < NT) STAGE(cur ^ 1, t + 1);  // issue next-tile loads FIRST
#pragma unroll
    for (int kk = 0; kk < 2; ++kk) {
      bf16x8 a[8], b[4];
#pragma unroll
      for (int i = 0; i < 8; ++i)
        a[i] = *(const bf16x8*)&As[cur][(wm * 128 + i * 16 + l15) * BK + kk * 32 + lk8];
#pragma unroll
      for (int j = 0; j < 4; ++j)
        b[j] = *(const bf16x8*)&Bs[cur][(wn * 64 + j * 16 + l15) * BK + kk * 32 + lk8];
#pragma unroll
      for (int i = 0; i < 8; ++i)
#pragma unroll
        for (int j = 0; j < 4; ++j)
          acc[i][j] = __builtin_amdgcn_mfma_f32_16x16x32_bf16(a[i], b[j], acc[i][j], 0, 0, 0);
    }
    __syncthreads();  // vmcnt(0)+lgkmcnt(0)+barrier: next tile landed, cur consumed
  }

  // ---- epilogue: C/D layout col = lane&15, row = (lane>>4)*4 + v  [m89/m91]
#pragma unroll
  for (int i = 0; i < 8; ++i) {
#pragma unroll
    for (int j = 0; j < 4; ++j) {
      const int col = n0 + wn * 64 + j * 16 + l15;
      const float bv = bias[col];
#pragma unroll
      for (int v = 0; v < 4; ++v) {
        const int row = m0 + wm * 128 + i * 16 + (lane >> 4) * 4 + v;
        const size_t o = (size_t)row * D_DIM + col;
        const float val = acc[i][j][v] + bv;
        if (GATE) {
          const float g = 1.f / (1.f + expf(-val));
          Ybf[o] = __float2bfloat16(g * __bfloat162float(ssm[o]));
        } else {
          Yf[o] = val;
        }
      }
    }
  }
}

// ---------------------------------------------------------------- launch
extern "C" void kernel_launch(void* const* d_in, const int* in_sizes, int n_in,
                              void* d_out, int out_size, void* d_ws, size_t ws_size,
                              hipStream_t stream) {
  const float* x  = (const float*)d_in[0];
  const float* A  = (const float*)d_in[1];
  const float* Bp = (const float*)d_in[2];
  const float* Cp = (const float*)d_in[3];
  const float* gw = (const float*)d_in[4];
  const float* gb = (const float*)d_in[5];
  const float* ow = (const float*)d_in[6];
  const float* ob = (const float*)d_in[7];
  float* out = (float*)d_out;

  // workspace layout (bytes)
  const size_t NEED = 73400320;
  if (ws_size < NEED) {
    fprintf(stderr, "kernel_launch: ws_size %zu < needed %zu\n", ws_size, NEED);
    return;
  }
  char* ws = (char*)d_ws;
  bf16*  x16   = (bf16*)(ws);                   // 33,554,432 B : x cast to bf16
  bf16*  ssm16 = (bf16*)(ws + 33554432);        // 33,554,432 B : ssm, then y in-place
  bf16*  gw16  = (bf16*)(ws + 67108864);        //  2,097,152 B
  bf16*  ow16  = (bf16*)(ws + 69206016);        //  2,097,152 B
  float* hfin  = (float*)(ws + 71303168);       //  1,048,576 B
  float* hin   = (float*)(ws + 72351744);       //  1,048,576 B

  cast_w_kernel<<<(D_DIM * D_DIM) / 256, 256, 0, stream>>>(gw, ow, gw16, ow16, D_DIM * D_DIM);
  ssm_pass1<<<B_DIM * NC * (D_DIM / 256), 256, 0, stream>>>(x, A, Bp, hfin);
  ssm_pass2<<<(B_DIM * D_DIM) / 256, 256, 0, stream>>>(A, hfin, hin);
  ssm_pass3<<<B_DIM * NC * (D_DIM / 256), 256, 0, stream>>>(x, A, Bp, Cp, hin, ssm16, x16);

  // gate GEMM: y = sigmoid(x@gw^T + gb) * ssm   (written in-place over ssm16)
  gemm256<true><<<GM * GN, 512, 0, stream>>>(x16, gw16, gb, ssm16, ssm16, nullptr);
  // out GEMM: out = y@ow^T + ob  (fp32)
  gemm256<false><<<GM * GN, 512, 0, stream>>>(ssm16, ow16, ob, nullptr, nullptr, out);
}

// Round 6
// 136.812 us; speedup vs baseline: 1.2417x; 1.1380x over previous
//
#include <hip/hip_runtime.h>
#include <hip/hip_bf16.h>
#include <cstdio>

typedef __hip_bfloat16 bf16;
typedef __bf16 bf16x8 __attribute__((ext_vector_type(8)));
typedef float f32x4 __attribute__((ext_vector_type(4)));

#define B_DIM 4
#define T_DIM 4096
#define D_DIM 1024
#define NC 64   // chunks along T
#define LC 64   // chunk length; NC*LC == T_DIM

#define M_DIM (B_DIM * T_DIM)  // 16384
#define BM 256
#define BN 256
#define BK 32
#define NT (D_DIM / BK)        // 32 K-tiles
#define GM (M_DIM / BM)        // 64
#define GN (D_DIM / BN)        // 4

// ---------------------------------------------------------------- weight cast
__global__ __launch_bounds__(256) void cast_w_kernel(
    const float* __restrict__ gw, const float* __restrict__ ow,
    bf16* __restrict__ gw16, bf16* __restrict__ ow16, int n) {
  int i = blockIdx.x * 256 + threadIdx.x;
  if (i < n) {
    gw16[i] = __float2bfloat16(gw[i]);
    ow16[i] = __float2bfloat16(ow[i]);
  }
}

// ---------------------------------------------------------------- SSM pass 1
__global__ __launch_bounds__(256) void ssm_pass1(
    const float* __restrict__ x, const float* __restrict__ A,
    const float* __restrict__ Bp, float* __restrict__ hfin) {
  const int tid  = threadIdx.x;
  const int dblk = blockIdx.x & 3;           // D/256 = 4
  const int c    = (blockIdx.x >> 2) & (NC - 1);
  const int b    = blockIdx.x >> 8;          // / (4*NC)
  const int d    = dblk * 256 + tid;
  const float a = A[d], bp = Bp[d];
  const float* p = x + ((size_t)(b * T_DIM + c * LC) * D_DIM + d);
  float h = 0.f;
#pragma unroll 4
  for (int i = 0; i < LC; ++i)
    h = fmaf(a, h, bp * p[(size_t)i * D_DIM]);
  hfin[(b * NC + c) * D_DIM + d] = h;
}

// ---------------------------------------------------------------- SSM pass 2
__global__ __launch_bounds__(256) void ssm_pass2(
    const float* __restrict__ A, const float* __restrict__ hfin,
    float* __restrict__ hin) {
  const int idx = blockIdx.x * 256 + threadIdx.x;  // B*D = 4096
  const int d = idx & (D_DIM - 1);
  const int b = idx >> 10;
  float aL = A[d];
#pragma unroll
  for (int s = 0; s < 6; ++s) aL *= aL;  // A^64 (LC = 2^6)
  float h = 0.f;
  for (int c = 0; c < NC; ++c) {
    const int o = (b * NC + c) * D_DIM + d;
    hin[o] = h;
    h = fmaf(aL, h, hfin[o]);
  }
}

// ---------------------------------------------------------------- SSM pass 3
__global__ __launch_bounds__(256) void ssm_pass3(
    const float* __restrict__ x, const float* __restrict__ A,
    const float* __restrict__ Bp, const float* __restrict__ Cp,
    const float* __restrict__ hin, bf16* __restrict__ ssm16,
    bf16* __restrict__ x16) {
  const int tid  = threadIdx.x;
  const int dblk = blockIdx.x & 3;
  const int c    = (blockIdx.x >> 2) & (NC - 1);
  const int b    = blockIdx.x >> 8;
  const int d    = dblk * 256 + tid;
  const float a = A[d], bp = Bp[d], cp = Cp[d];
  float h = hin[(b * NC + c) * D_DIM + d];
  const size_t base = (size_t)(b * T_DIM + c * LC) * D_DIM + d;
#pragma unroll 4
  for (int i = 0; i < LC; ++i) {
    const size_t o = base + (size_t)i * D_DIM;
    const float xv = x[o];
    h = fmaf(a, h, bp * xv);
    ssm16[o] = __float2bfloat16(cp * h);
    x16[o]  = __float2bfloat16(xv);
  }
}

// ---------------------------------------------------------------- GEMM 256x256
// C[m][e] = sum_k X[m][k] * W[e][k]  (+bias, +epilogue)
// 256x256 tile, BK=32, 8 waves (2M x 4N), per-wave C = 128x64 (8x4 frags).
// Ring-4 LDS (4 x 32 KiB), prefetch distance 3, counted vmcnt(8) (T4),
// XOR bank swizzle slot^=(row>>1)&3 applied on BOTH global src and ds_read
// (rule #21), setprio around the 32-MFMA cluster (T5), raw s_barrier pairs.
template <bool GATE>
__global__ __launch_bounds__(512) void gemm256(
    const bf16* __restrict__ Xm, const bf16* __restrict__ Wm,
    const float* __restrict__ bias, const bf16* __restrict__ ssm,
    bf16* __restrict__ Ybf, float* __restrict__ Yf) {
  // buf layout (shorts): [0,8192) = A tile 256x32, [8192,16384) = B tile 256x32
  __shared__ __align__(16) short LDS[4][16384];  // 4 x 32 KiB = 128 KiB

  const int tid  = threadIdx.x;
  const int lane = tid & 63;
  const int wave = tid >> 6;
  const int wm = wave >> 2;           // 0..1
  const int wn = wave & 3;            // 0..3
  const int l15 = lane & 15;
  // swizzled ds_read slot: true chunk (lane>>4), row parity term (l15>>1)&3
  const int sA = ((lane >> 4) ^ ((l15 >> 1) & 3)) << 3;  // shorts

  // XCD-chunked swizzle (256 blocks, 8 XCDs): 4 N-blocks per M-row share L2.
  const int bid = blockIdx.x;
  const int swz = (bid & 7) * (GM * GN / 8) + (bid >> 3);
  const int m0 = (swz >> 2) * BM;
  const int n0 = (swz & 3) * BN;

  // staging: tile = A(1024 chunks of 16B) + B(1024). Per issue 512 threads.
  // linear LDS chunk cid -> row=cid>>2, slot=cid&3; global col-chunk
  // c = slot ^ ((row>>1)&3)  (involution matches sA on the read side).
  const int row0 = tid >> 2;
  const int c0   = (tid & 3) ^ ((row0 >> 1) & 3);
  const size_t offA0 = (size_t)(m0 + row0) * D_DIM + c0 * 8;
  const size_t offB0 = (size_t)(n0 + row0) * D_DIM + c0 * 8;

  auto gll = [](const bf16* g, short* l) {
    __builtin_amdgcn_global_load_lds(
        (const __attribute__((address_space(1))) void*)g,
        (__attribute__((address_space(3))) void*)l, 16, 0, 0);
  };
  auto STAGE = [&](int buf, int kt) {
    const size_t ko = (size_t)kt * BK;
    short* b0 = &LDS[buf][0] + wave * 512;
    gll(Xm + offA0 + ko,               b0);
    gll(Xm + offA0 + 128 * D_DIM + ko, b0 + 4096);
    gll(Wm + offB0 + ko,               b0 + 8192);
    gll(Wm + offB0 + 128 * D_DIM + ko, b0 + 12288);
  };

  f32x4 acc[8][4] = {};

  // prologue: prime tiles 0,1,2 (12 loads/wave in flight)
  STAGE(0, 0);
  STAGE(1, 1);
  STAGE(2, 2);

#define KTILE_BODY(T_, VM_N, DO_STAGE)                                      \
  {                                                                         \
    asm volatile("s_waitcnt vmcnt(" #VM_N ")" ::: "memory");                \
    __builtin_amdgcn_s_barrier();                                           \
    if (DO_STAGE) STAGE(((T_) + 3) & 3, (T_) + 3);                          \
    const short* bb = &LDS[(T_) & 3][0];                                    \
    bf16x8 a[8], b[4];                                                      \
    _Pragma("unroll")                                                       \
    for (int i = 0; i < 8; ++i)                                             \
      a[i] = *(const bf16x8*)(bb + (wm * 128 + i * 16 + l15) * BK + sA);    \
    _Pragma("unroll")                                                       \
    for (int j = 0; j < 4; ++j)                                             \
      b[j] = *(const bf16x8*)(bb + 8192 + (wn * 64 + j * 16 + l15) * BK + sA); \
    asm volatile("s_waitcnt lgkmcnt(0)" ::: "memory");                      \
    __builtin_amdgcn_sched_barrier(0);                                      \
    __builtin_amdgcn_s_setprio(1);                                          \
    _Pragma("unroll")                                                       \
    for (int i = 0; i < 8; ++i)                                             \
      _Pragma("unroll")                                                     \
      for (int j = 0; j < 4; ++j)                                           \
        acc[i][j] =                                                         \
            __builtin_amdgcn_mfma_f32_16x16x32_bf16(a[i], b[j], acc[i][j], 0, 0, 0); \
    __builtin_amdgcn_s_setprio(0);                                          \
    __builtin_amdgcn_s_barrier();                                           \
  }

  for (int t = 0; t < NT - 3; ++t)  // t = 0..28: stage t+3 = 3..31
    KTILE_BODY(t, 8, true);
  KTILE_BODY(NT - 3, 8, false);     // tiles 30,31 in flight (8 loads)
  KTILE_BODY(NT - 2, 4, false);     // tile 31 in flight (4 loads)
  KTILE_BODY(NT - 1, 0, false);     // drain
#undef KTILE_BODY

  // ---- epilogue: C/D layout col = lane&15, row = (lane>>4)*4 + v  [m89/m91]
#pragma unroll
  for (int i = 0; i < 8; ++i) {
#pragma unroll
    for (int j = 0; j < 4; ++j) {
      const int col = n0 + wn * 64 + j * 16 + l15;
      const float bv = bias[col];
#pragma unroll
      for (int v = 0; v < 4; ++v) {
        const int row = m0 + wm * 128 + i * 16 + (lane >> 4) * 4 + v;
        const size_t o = (size_t)row * D_DIM + col;
        const float val = acc[i][j][v] + bv;
        if (GATE) {
          const float g = 1.f / (1.f + expf(-val));
          Ybf[o] = __float2bfloat16(g * __bfloat162float(ssm[o]));
        } else {
          Yf[o] = val;
        }
      }
    }
  }
}

// ---------------------------------------------------------------- launch
extern "C" void kernel_launch(void* const* d_in, const int* in_sizes, int n_in,
                              void* d_out, int out_size, void* d_ws, size_t ws_size,
                              hipStream_t stream) {
  const float* x  = (const float*)d_in[0];
  const float* A  = (const float*)d_in[1];
  const float* Bp = (const float*)d_in[2];
  const float* Cp = (const float*)d_in[3];
  const float* gw = (const float*)d_in[4];
  const float* gb = (const float*)d_in[5];
  const float* ow = (const float*)d_in[6];
  const float* ob = (const float*)d_in[7];
  float* out = (float*)d_out;

  // workspace layout (bytes)
  const size_t NEED = 73400320;
  if (ws_size < NEED) {
    fprintf(stderr, "kernel_launch: ws_size %zu < needed %zu\n", ws_size, NEED);
    return;
  }
  char* ws = (char*)d_ws;
  bf16*  x16   = (bf16*)(ws);                   // 33,554,432 B : x cast to bf16
  bf16*  ssm16 = (bf16*)(ws + 33554432);        // 33,554,432 B : ssm, then y in-place
  bf16*  gw16  = (bf16*)(ws + 67108864);        //  2,097,152 B
  bf16*  ow16  = (bf16*)(ws + 69206016);        //  2,097,152 B
  float* hfin  = (float*)(ws + 71303168);       //  1,048,576 B
  float* hin   = (float*)(ws + 72351744);       //  1,048,576 B

  cast_w_kernel<<<(D_DIM * D_DIM) / 256, 256, 0, stream>>>(gw, ow, gw16, ow16, D_DIM * D_DIM);
  ssm_pass1<<<B_DIM * NC * (D_DIM / 256), 256, 0, stream>>>(x, A, Bp, hfin);
  ssm_pass2<<<(B_DIM * D_DIM) / 256, 256, 0, stream>>>(A, hfin, hin);
  ssm_pass3<<<B_DIM * NC * (D_DIM / 256), 256, 0, stream>>>(x, A, Bp, Cp, hin, ssm16, x16);

  // gate GEMM: y = sigmoid(x@gw^T + gb) * ssm   (written in-place over ssm16)
  gemm256<true><<<GM * GN, 512, 0, stream>>>(x16, gw16, gb, ssm16, ssm16, nullptr);
  // out GEMM: out = y@ow^T + ob  (fp32)
  gemm256<false><<<GM * GN, 512, 0, stream>>>(ssm16, ow16, ob, nullptr, nullptr, out);
}

// Round 7
// 130.266 us; speedup vs baseline: 1.3041x; 1.0503x over previous
//
#include <hip/hip_runtime.h>
#include <hip/hip_bf16.h>
#include <cstdio>

typedef __hip_bfloat16 bf16;
typedef __bf16 bf16x8 __attribute__((ext_vector_type(8)));
typedef float f32x4 __attribute__((ext_vector_type(4)));

#define B_DIM 4
#define T_DIM 4096
#define D_DIM 1024
#define NC 64   // chunks along T
#define LC 64   // chunk length; NC*LC == T_DIM

#define M_DIM (B_DIM * T_DIM)  // 16384
#define BM 256
#define BN 256
#define BK 32
#define NT (D_DIM / BK)        // 32 K-tiles
#define GM (M_DIM / BM)        // 64
#define GN (D_DIM / BN)        // 4

// ---------------------------------------------------------------- weight cast
__global__ __launch_bounds__(256) void cast_w_kernel(
    const float* __restrict__ gw, const float* __restrict__ ow,
    bf16* __restrict__ gw16, bf16* __restrict__ ow16, int n) {
  int i = blockIdx.x * 256 + threadIdx.x;
  if (i < n) {
    gw16[i] = __float2bfloat16(gw[i]);
    ow16[i] = __float2bfloat16(ow[i]);
  }
}

// ---------------------------------------------------------------- SSM pass 1
__global__ __launch_bounds__(256) void ssm_pass1(
    const float* __restrict__ x, const float* __restrict__ A,
    const float* __restrict__ Bp, float* __restrict__ hfin) {
  const int tid  = threadIdx.x;
  const int dblk = blockIdx.x & 3;           // D/256 = 4
  const int c    = (blockIdx.x >> 2) & (NC - 1);
  const int b    = blockIdx.x >> 8;          // / (4*NC)
  const int d    = dblk * 256 + tid;
  const float a = A[d], bp = Bp[d];
  const float* p = x + ((size_t)(b * T_DIM + c * LC) * D_DIM + d);
  float h = 0.f;
#pragma unroll 4
  for (int i = 0; i < LC; ++i)
    h = fmaf(a, h, bp * p[(size_t)i * D_DIM]);
  hfin[(b * NC + c) * D_DIM + d] = h;
}

// ---------------------------------------------------------------- SSM pass 2
__global__ __launch_bounds__(256) void ssm_pass2(
    const float* __restrict__ A, const float* __restrict__ hfin,
    float* __restrict__ hin) {
  const int idx = blockIdx.x * 256 + threadIdx.x;  // B*D = 4096
  const int d = idx & (D_DIM - 1);
  const int b = idx >> 10;
  float aL = A[d];
#pragma unroll
  for (int s = 0; s < 6; ++s) aL *= aL;  // A^64 (LC = 2^6)
  float h = 0.f;
  for (int c = 0; c < NC; ++c) {
    const int o = (b * NC + c) * D_DIM + d;
    hin[o] = h;
    h = fmaf(aL, h, hfin[o]);
  }
}

// ---------------------------------------------------------------- SSM pass 3
__global__ __launch_bounds__(256) void ssm_pass3(
    const float* __restrict__ x, const float* __restrict__ A,
    const float* __restrict__ Bp, const float* __restrict__ Cp,
    const float* __restrict__ hin, bf16* __restrict__ ssm16,
    bf16* __restrict__ x16) {
  const int tid  = threadIdx.x;
  const int dblk = blockIdx.x & 3;
  const int c    = (blockIdx.x >> 2) & (NC - 1);
  const int b    = blockIdx.x >> 8;
  const int d    = dblk * 256 + tid;
  const float a = A[d], bp = Bp[d], cp = Cp[d];
  float h = hin[(b * NC + c) * D_DIM + d];
  const size_t base = (size_t)(b * T_DIM + c * LC) * D_DIM + d;
#pragma unroll 4
  for (int i = 0; i < LC; ++i) {
    const size_t o = base + (size_t)i * D_DIM;
    const float xv = x[o];
    h = fmaf(a, h, bp * xv);
    ssm16[o] = __float2bfloat16(cp * h);
    x16[o]  = __float2bfloat16(xv);
  }
}

// ---------------------------------------------------------------- GEMM 256x256
// C[m][e] = sum_k X[m][k] * W[e][k]  (+bias, +epilogue)
// 256x256 tile, BK=32, 8 waves (2M x 4N), per-wave C = 128x64 (8x4 frags).
// Ring-4 LDS, prefetch distance 3, counted vmcnt (T4), T2 XOR swizzle
// (both-sides), T5 setprio. R7: SINGLE mid-tile barrier + split-MFMA:
//   top:  ds_read 12 frags(t); STAGE(t+3); lgkmcnt(0); MFMA half1 (16)
//   mid:  vmcnt(N); s_barrier            // t+1 staged for ALL waves
//         MFMA half2 (16, reg-only, overlaps next tile's reads)
// Lifetime audit: reads of buf[t] finish before tile t's mid-barrier, so
// STAGE(t+3) (same ring slot as t-1) issued after that barrier is safe;
// vmcnt(4*(#staged tiles > t+1)) = 8/4/0 guarantees buf[t+1] complete.
template <bool GATE>
__global__ __launch_bounds__(512) void gemm256(
    const bf16* __restrict__ Xm, const bf16* __restrict__ Wm,
    const float* __restrict__ bias, const bf16* __restrict__ ssm,
    bf16* __restrict__ Ybf, float* __restrict__ Yf) {
  // buf layout (shorts): [0,8192) = A tile 256x32, [8192,16384) = B tile 256x32
  __shared__ __align__(16) short LDS[4][16384];  // 4 x 32 KiB = 128 KiB

  const int tid  = threadIdx.x;
  const int lane = tid & 63;
  const int wave = tid >> 6;
  const int wm = wave >> 2;           // 0..1
  const int wn = wave & 3;            // 0..3
  const int l15 = lane & 15;
  // swizzled ds_read slot: true chunk (lane>>4), row parity term (l15>>1)&3
  const int sA = ((lane >> 4) ^ ((l15 >> 1) & 3)) << 3;  // shorts

  // XCD-chunked swizzle (256 blocks, 8 XCDs): 4 N-blocks per M-row share L2.
  const int bid = blockIdx.x;
  const int swz = (bid & 7) * (GM * GN / 8) + (bid >> 3);
  const int m0 = (swz >> 2) * BM;
  const int n0 = (swz & 3) * BN;

  // staging: linear LDS chunk cid -> row=cid>>2, slot=cid&3; global col-chunk
  // c = slot ^ ((row>>1)&3)  (involution matches sA on the read side).
  const int row0 = tid >> 2;
  const int c0   = (tid & 3) ^ ((row0 >> 1) & 3);
  const size_t offA0 = (size_t)(m0 + row0) * D_DIM + c0 * 8;
  const size_t offB0 = (size_t)(n0 + row0) * D_DIM + c0 * 8;

  auto gll = [](const bf16* g, short* l) {
    __builtin_amdgcn_global_load_lds(
        (const __attribute__((address_space(1))) void*)g,
        (__attribute__((address_space(3))) void*)l, 16, 0, 0);
  };
  auto STAGE = [&](int buf, int kt) {
    const size_t ko = (size_t)kt * BK;
    short* b0 = &LDS[buf][0] + wave * 512;
    gll(Xm + offA0 + ko,               b0);
    gll(Xm + offA0 + 128 * D_DIM + ko, b0 + 4096);
    gll(Wm + offB0 + ko,               b0 + 8192);
    gll(Wm + offB0 + 128 * D_DIM + ko, b0 + 12288);
  };

  f32x4 acc[8][4] = {};

  // prologue: prime tiles 0,1,2 (12 loads/wave in flight)
  STAGE(0, 0);
  STAGE(1, 1);
  STAGE(2, 2);
  asm volatile("s_waitcnt vmcnt(8)" ::: "memory");
  __builtin_amdgcn_s_barrier();  // tile 0 staged for all waves

#define KTILE_BODY(T_, VMSTR, DO_STAGE, DO_BAR)                             \
  {                                                                         \
    const short* bb = &LDS[(T_) & 3][0];                                    \
    bf16x8 a[8], b[4];                                                      \
    _Pragma("unroll")                                                       \
    for (int i = 0; i < 8; ++i)                                             \
      a[i] = *(const bf16x8*)(bb + (wm * 128 + i * 16 + l15) * BK + sA);    \
    _Pragma("unroll")                                                       \
    for (int j = 0; j < 4; ++j)                                             \
      b[j] = *(const bf16x8*)(bb + 8192 + (wn * 64 + j * 16 + l15) * BK + sA); \
    if (DO_STAGE) STAGE(((T_) + 3) & 3, (T_) + 3);                          \
    asm volatile("s_waitcnt lgkmcnt(0)" ::: "memory");                      \
    __builtin_amdgcn_sched_barrier(0);                                      \
    __builtin_amdgcn_s_setprio(1);                                          \
    _Pragma("unroll")                                                       \
    for (int i = 0; i < 4; ++i)                                             \
      _Pragma("unroll")                                                     \
      for (int j = 0; j < 4; ++j)                                           \
        acc[i][j] =                                                         \
            __builtin_amdgcn_mfma_f32_16x16x32_bf16(a[i], b[j], acc[i][j], 0, 0, 0); \
    __builtin_amdgcn_s_setprio(0);                                          \
    if (DO_BAR) {                                                           \
      asm volatile("s_waitcnt " VMSTR ::: "memory");                        \
      __builtin_amdgcn_s_barrier();                                         \
    }                                                                       \
    __builtin_amdgcn_s_setprio(1);                                          \
    _Pragma("unroll")                                                       \
    for (int i = 4; i < 8; ++i)                                             \
      _Pragma("unroll")                                                     \
      for (int j = 0; j < 4; ++j)                                           \
        acc[i][j] =                                                         \
            __builtin_amdgcn_mfma_f32_16x16x32_bf16(a[i], b[j], acc[i][j], 0, 0, 0); \
    __builtin_amdgcn_s_setprio(0);                                          \
  }

  for (int t = 0; t < NT - 3; ++t)        // t = 0..28: stage t+3 = 3..31
    KTILE_BODY(t, "vmcnt(8)", true, true);
  KTILE_BODY(NT - 3, "vmcnt(4)", false, true);  // ensure tile NT-2 landed
  KTILE_BODY(NT - 2, "vmcnt(0)", false, true);  // ensure tile NT-1 landed
  KTILE_BODY(NT - 1, "vmcnt(0)", false, false); // last tile: no barrier
#undef KTILE_BODY

  // ---- epilogue: C/D layout col = lane&15, row = (lane>>4)*4 + v  [m89/m91]
#pragma unroll
  for (int i = 0; i < 8; ++i) {
#pragma unroll
    for (int j = 0; j < 4; ++j) {
      const int col = n0 + wn * 64 + j * 16 + l15;
      const float bv = bias[col];
#pragma unroll
      for (int v = 0; v < 4; ++v) {
        const int row = m0 + wm * 128 + i * 16 + (lane >> 4) * 4 + v;
        const size_t o = (size_t)row * D_DIM + col;
        const float val = acc[i][j][v] + bv;
        if (GATE) {
          const float g = 1.f / (1.f + expf(-val));
          Ybf[o] = __float2bfloat16(g * __bfloat162float(ssm[o]));
        } else {
          Yf[o] = val;
        }
      }
    }
  }
}

// ---------------------------------------------------------------- launch
extern "C" void kernel_launch(void* const* d_in, const int* in_sizes, int n_in,
                              void* d_out, int out_size, void* d_ws, size_t ws_size,
                              hipStream_t stream) {
  const float* x  = (const float*)d_in[0];
  const float* A  = (const float*)d_in[1];
  const float* Bp = (const float*)d_in[2];
  const float* Cp = (const float*)d_in[3];
  const float* gw = (const float*)d_in[4];
  const float* gb = (const float*)d_in[5];
  const float* ow = (const float*)d_in[6];
  const float* ob = (const float*)d_in[7];
  float* out = (float*)d_out;

  // workspace layout (bytes)
  const size_t NEED = 73400320;
  if (ws_size < NEED) {
    fprintf(stderr, "kernel_launch: ws_size %zu < needed %zu\n", ws_size, NEED);
    return;
  }
  char* ws = (char*)d_ws;
  bf16*  x16   = (bf16*)(ws);                   // 33,554,432 B : x cast to bf16
  bf16*  ssm16 = (bf16*)(ws + 33554432);        // 33,554,432 B : ssm, then y in-place
  bf16*  gw16  = (bf16*)(ws + 67108864);        //  2,097,152 B
  bf16*  ow16  = (bf16*)(ws + 69206016);        //  2,097,152 B
  float* hfin  = (float*)(ws + 71303168);       //  1,048,576 B
  float* hin   = (float*)(ws + 72351744);       //  1,048,576 B

  cast_w_kernel<<<(D_DIM * D_DIM) / 256, 256, 0, stream>>>(gw, ow, gw16, ow16, D_DIM * D_DIM);
  ssm_pass1<<<B_DIM * NC * (D_DIM / 256), 256, 0, stream>>>(x, A, Bp, hfin);
  ssm_pass2<<<(B_DIM * D_DIM) / 256, 256, 0, stream>>>(A, hfin, hin);
  ssm_pass3<<<B_DIM * NC * (D_DIM / 256), 256, 0, stream>>>(x, A, Bp, Cp, hin, ssm16, x16);

  // gate GEMM: y = sigmoid(x@gw^T + gb) * ssm   (written in-place over ssm16)
  gemm256<true><<<GM * GN, 512, 0, stream>>>(x16, gw16, gb, ssm16, ssm16, nullptr);
  // out GEMM: out = y@ow^T + ob  (fp32)
  gemm256<false><<<GM * GN, 512, 0, stream>>>(ssm16, ow16, ob, nullptr, nullptr, out);
}